// Round 8
// baseline (233.000 us; speedup 1.0000x reference)
//
#include <hip/hip_runtime.h>

#define EPS 1e-8f
#define LOG2E 1.4426950408889634f

typedef float f32x4 __attribute__((ext_vector_type(4)));

// X(m) = exp2(-log2e * exp2(k1 * D(m))) * mask(m), k1 = -sigma^2*log2e
// D >= 0 -> inner exp2 in (0,1]; outer arg in [-log2e,0) -> both exact-range-safe.
#define CALC(c0, c1, c2, mval, cn0, cn1, cn2, sqn, k1)           \
    ({                                                           \
        float _sqm = (c0)*(c0) + (c1)*(c1) + (c2)*(c2);          \
        float _dot = (cn0)*(c0) + (cn1)*(c1) + (cn2)*(c2);       \
        float _D   = (sqn) + _sqm - 2.0f * _dot;                 \
        float _A   = __builtin_amdgcn_exp2f((k1) * _D);          \
        __builtin_amdgcn_exp2f(-LOG2E * _A) * (mval);            \
    })

// Fast path, N == 1024: ONE WAVE PER ROW. 64 lanes x 16 m's each, arranged as
// 4 interleaved chunks of 256 columns (lane gets 4 consecutive floats per
// chunk): every mask load / output store is 1 KB contiguous per wave. 4
// independent nontemporal mask loads in flight per lane (vs 1 in the
// block-per-row version), row-sum entirely in-wave via shfl_xor — no LDS, no
// __syncthreads, waves retire independently. Block = 4 waves = 4 rows.
__global__ __launch_bounds__(256) void gaussian_rownorm_1024(
    const float* __restrict__ C,        // [B, 1024, 3]
    const float* __restrict__ masks,    // [B, 1024, 1024]
    const float* __restrict__ inv_sigma,// [1]
    float* __restrict__ out)            // [B, 1024, 1024]
{
    constexpr int N = 1024;
    const int wid  = threadIdx.x >> 6;
    const int lane = threadIdx.x & 63;
    const int row  = blockIdx.x * 4 + wid;   // global row = b*N + n
    const int b    = row >> 10;
    const int n    = row & (N - 1);

    const float s  = inv_sigma[0];
    const float k1 = -(s * s) * LOG2E;

    const float* __restrict__ Cb = C + (size_t)b * N * 3;
    const float cn0 = Cb[n * 3 + 0];
    const float cn1 = Cb[n * 3 + 1];
    const float cn2 = Cb[n * 3 + 2];
    const float sqn = cn0 * cn0 + cn1 * cn1 + cn2 * cn2;

    const size_t rowbase = (size_t)row * N;

    // Issue all 4 mask loads up front (4 outstanding HBM loads per lane).
    f32x4 mk[4];
    #pragma unroll
    for (int k = 0; k < 4; ++k)
        mk[k] = __builtin_nontemporal_load(
            (const f32x4*)(masks + rowbase + k * 256 + lane * 4));

    float x[16];
    float psum = 0.0f;
    #pragma unroll
    for (int k = 0; k < 4; ++k) {
        const int m0 = k * 256 + lane * 4;          // 4 consecutive m's
        const f32x4* __restrict__ cm = (const f32x4*)(Cb + m0 * 3);
        const f32x4 ca  = cm[0];   // m0: ca.x ca.y ca.z | m1: ca.w ...
        const f32x4 cb4 = cm[1];   // m1: cb4.x cb4.y    | m2: cb4.z cb4.w
        const f32x4 cc  = cm[2];   // m2: cc.x           | m3: cc.y cc.z cc.w

        x[k*4+0] = CALC(ca.x,  ca.y,  ca.z,  mk[k].x, cn0, cn1, cn2, sqn, k1);
        x[k*4+1] = CALC(ca.w,  cb4.x, cb4.y, mk[k].y, cn0, cn1, cn2, sqn, k1);
        x[k*4+2] = CALC(cb4.z, cb4.w, cc.x,  mk[k].z, cn0, cn1, cn2, sqn, k1);
        x[k*4+3] = CALC(cc.y,  cc.z,  cc.w,  mk[k].w, cn0, cn1, cn2, sqn, k1);
        psum += (x[k*4+0] + x[k*4+1]) + (x[k*4+2] + x[k*4+3]);
    }

    // In-wave row-sum: 6-step butterfly, no LDS, no barrier.
    #pragma unroll
    for (int off = 32; off > 0; off >>= 1)
        psum += __shfl_xor(psum, off, 64);

    const float r = 1.0f / (psum + EPS);

    #pragma unroll
    for (int k = 0; k < 4; ++k) {
        f32x4 o;
        o.x = x[k*4+0] * r; o.y = x[k*4+1] * r;
        o.z = x[k*4+2] * r; o.w = x[k*4+3] * r;
        __builtin_nontemporal_store(o, (f32x4*)(out + rowbase + k * 256 + lane * 4));
    }
}

// Generic fallback (any N % 4 == 0): block per row, verified in R1/R6.
__global__ __launch_bounds__(256) void gaussian_rownorm_generic(
    const float* __restrict__ C,
    const float* __restrict__ masks,
    const float* __restrict__ inv_sigma,
    float* __restrict__ out,
    int N)
{
    const int n = blockIdx.x;
    const int b = blockIdx.y;
    const int t = threadIdx.x;

    const float s  = inv_sigma[0];
    const float k1 = -(s * s) * LOG2E;

    const float* __restrict__ Cb = C + (size_t)b * N * 3;
    const float cn0 = Cb[n * 3 + 0];
    const float cn1 = Cb[n * 3 + 1];
    const float cn2 = Cb[n * 3 + 2];
    const float sqn = cn0 * cn0 + cn1 * cn1 + cn2 * cn2;

    const int m0 = t * 4;
    const f32x4* __restrict__ cm = (const f32x4*)(Cb + (size_t)m0 * 3);
    const f32x4 ca  = cm[0];
    const f32x4 cb4 = cm[1];
    const f32x4 cc  = cm[2];

    const size_t rowbase = ((size_t)b * N + n) * N;
    const f32x4 mk = __builtin_nontemporal_load((const f32x4*)(masks + rowbase + m0));

    const float x0 = CALC(ca.x,  ca.y,  ca.z,  mk.x, cn0, cn1, cn2, sqn, k1);
    const float x1 = CALC(ca.w,  cb4.x, cb4.y, mk.y, cn0, cn1, cn2, sqn, k1);
    const float x2 = CALC(cb4.z, cb4.w, cc.x,  mk.z, cn0, cn1, cn2, sqn, k1);
    const float x3 = CALC(cc.y,  cc.z,  cc.w,  mk.w, cn0, cn1, cn2, sqn, k1);

    float psum = (x0 + x1) + (x2 + x3);
    #pragma unroll
    for (int off = 32; off > 0; off >>= 1)
        psum += __shfl_xor(psum, off, 64);

    __shared__ float wsum[4];
    const int wid = t >> 6;
    if ((t & 63) == 0) wsum[wid] = psum;
    __syncthreads();

    const float total = wsum[0] + wsum[1] + wsum[2] + wsum[3];
    const float r = 1.0f / (total + EPS);

    f32x4 o;
    o.x = x0 * r; o.y = x1 * r; o.z = x2 * r; o.w = x3 * r;
    __builtin_nontemporal_store(o, (f32x4*)(out + rowbase + m0));
}

extern "C" void kernel_launch(void* const* d_in, const int* in_sizes, int n_in,
                              void* d_out, int out_size, void* d_ws, size_t ws_size,
                              hipStream_t stream) {
    const float* C         = (const float*)d_in[0];  // [B, N, 3]
    const float* masks     = (const float*)d_in[1];  // [B, N, N]
    const float* inv_sigma = (const float*)d_in[2];  // [1]
    float* out             = (float*)d_out;          // [B, N, N]

    const long long N_ll = (long long)out_size * 3LL / (long long)in_sizes[0];
    const int N = (int)N_ll;
    const int B = in_sizes[0] / (3 * N);

    if (N == 1024 && (B * N) % 4 == 0) {
        const int grid = B * N / 4;     // 4 rows (waves) per block
        gaussian_rownorm_1024<<<grid, 256, 0, stream>>>(C, masks, inv_sigma, out);
    } else {
        dim3 grid(N, B);
        gaussian_rownorm_generic<<<grid, N / 4, 0, stream>>>(C, masks, inv_sigma, out, N);
    }
}

// Round 10
// 232.829 us; speedup vs baseline: 1.0007x; 1.0007x over previous
//
#include <hip/hip_runtime.h>

#define EPS 1e-8f
#define LOG2E 1.4426950408889634f

typedef float f32x4 __attribute__((ext_vector_type(4)));

// X(m) = exp2(-log2e * exp2(k1 * D(m))) * mask(m), k1 = -sigma^2*log2e
// D >= 0 -> inner exp2 in (0,1]; outer arg in [-log2e,0) -> range-safe.
__device__ __forceinline__ float calcx(float c0, float c1, float c2, float mval,
                                       float cn0, float cn1, float cn2,
                                       float sqn, float k1) {
    float sqm = c0*c0 + c1*c1 + c2*c2;
    float dot = cn0*c0 + cn1*c1 + cn2*c2;
    float D   = sqn + sqm - 2.0f*dot;
    float A   = __builtin_amdgcn_exp2f(k1 * D);
    return __builtin_amdgcn_exp2f(-LOG2E * A) * mval;
}

// Compute one full row from prefetched mask regs + hoisted C columns; store.
__device__ __forceinline__ void do_row(const f32x4 (&cm)[12],
                                       f32x4 m0, f32x4 m1, f32x4 m2, f32x4 m3,
                                       float cn0, float cn1, float cn2,
                                       float sqn, float k1,
                                       float* __restrict__ outp) {
    float x[16];
    float ps = 0.0f;
    #pragma unroll
    for (int k = 0; k < 4; ++k) {
        const f32x4 a = cm[k*3+0], b = cm[k*3+1], c = cm[k*3+2];
        const f32x4 mv = (k == 0) ? m0 : (k == 1) ? m1 : (k == 2) ? m2 : m3;
        x[k*4+0] = calcx(a.x, a.y, a.z, mv.x, cn0, cn1, cn2, sqn, k1);
        x[k*4+1] = calcx(a.w, b.x, b.y, mv.y, cn0, cn1, cn2, sqn, k1);
        x[k*4+2] = calcx(b.z, b.w, c.x, mv.z, cn0, cn1, cn2, sqn, k1);
        x[k*4+3] = calcx(c.y, c.z, c.w, mv.w, cn0, cn1, cn2, sqn, k1);
        ps += (x[k*4+0] + x[k*4+1]) + (x[k*4+2] + x[k*4+3]);
    }
    #pragma unroll
    for (int off = 32; off > 0; off >>= 1)
        ps += __shfl_xor(ps, off, 64);
    const float r = 1.0f / (ps + EPS);
    #pragma unroll
    for (int k = 0; k < 4; ++k) {
        f32x4 o;
        o.x = x[k*4+0]*r; o.y = x[k*4+1]*r; o.z = x[k*4+2]*r; o.w = x[k*4+3]*r;
        __builtin_nontemporal_store(o, (f32x4*)(outp + k*256));
    }
}

// N == 1024 fast path: one wave handles 4 CONSECUTIVE rows with a 2-deep
// software pipeline (prefetch row r+1's masks while computing row r), so the
// wave keeps HBM loads in flight across its compute phases. The lane's 16
// C-columns are row-invariant -> hoisted into cm[12] once per wave. Query
// points for all 4 rows hoisted up front. No LDS, no barriers.
__global__ __launch_bounds__(256) void gaussian_rownorm_1024(
    const float* __restrict__ C,        // [B, 1024, 3]
    const float* __restrict__ masks,    // [B, 1024, 1024]
    const float* __restrict__ inv_sigma,// [1]
    float* __restrict__ out)            // [B, 1024, 1024]
{
    constexpr int N = 1024;
    const int wid  = threadIdx.x >> 6;
    const int lane = threadIdx.x & 63;
    const int row0 = (blockIdx.x * 4 + wid) * 4;  // 4 consecutive rows
    const int b    = row0 >> 10;                  // same batch for all 4

    const float s  = inv_sigma[0];
    const float k1 = -(s * s) * LOG2E;

    const float* __restrict__ Cb = C + (size_t)b * N * 3;

    // Hoisted neighbor coords for this lane's 16 columns (row-invariant).
    f32x4 cm[12];
    #pragma unroll
    for (int k = 0; k < 4; ++k) {
        const f32x4* p = (const f32x4*)(Cb + (size_t)(k*256 + lane*4) * 3);
        cm[k*3+0] = p[0]; cm[k*3+1] = p[1]; cm[k*3+2] = p[2];
    }

    // Hoisted query points for the 4 rows.
    float cn0[4], cn1[4], cn2[4], sqn[4];
    #pragma unroll
    for (int r = 0; r < 4; ++r) {
        const int n = (row0 + r) & (N - 1);
        cn0[r] = Cb[n*3+0]; cn1[r] = Cb[n*3+1]; cn2[r] = Cb[n*3+2];
        sqn[r] = cn0[r]*cn0[r] + cn1[r]*cn1[r] + cn2[r]*cn2[r];
    }

    const float* mbase = masks + (size_t)row0 * N + lane * 4;
    float*       obase = out   + (size_t)row0 * N + lane * 4;

    #define LOADM(d0, d1, d2, d3, r) do {                         \
        const float* _p = mbase + (size_t)(r) * N;                \
        d0 = *(const f32x4*)(_p +   0);                           \
        d1 = *(const f32x4*)(_p + 256);                           \
        d2 = *(const f32x4*)(_p + 512);                           \
        d3 = *(const f32x4*)(_p + 768);                           \
    } while (0)

    f32x4 a0, a1, a2, a3;   // ping buffer
    f32x4 b0, b1, b2, b3;   // pong buffer

    LOADM(a0, a1, a2, a3, 0);
    LOADM(b0, b1, b2, b3, 1);   // in flight during row 0 compute
    do_row(cm, a0, a1, a2, a3, cn0[0], cn1[0], cn2[0], sqn[0], k1, obase + 0*N);
    LOADM(a0, a1, a2, a3, 2);   // in flight during row 1 compute
    do_row(cm, b0, b1, b2, b3, cn0[1], cn1[1], cn2[1], sqn[1], k1, obase + 1*N);
    LOADM(b0, b1, b2, b3, 3);   // in flight during row 2 compute
    do_row(cm, a0, a1, a2, a3, cn0[2], cn1[2], cn2[2], sqn[2], k1, obase + 2*N);
    do_row(cm, b0, b1, b2, b3, cn0[3], cn1[3], cn2[3], sqn[3], k1, obase + 3*N);
    #undef LOADM
}

// Generic fallback (any N % 4 == 0): block per row, verified in R1/R6.
__global__ __launch_bounds__(256) void gaussian_rownorm_generic(
    const float* __restrict__ C,
    const float* __restrict__ masks,
    const float* __restrict__ inv_sigma,
    float* __restrict__ out,
    int N)
{
    const int n = blockIdx.x;
    const int b = blockIdx.y;
    const int t = threadIdx.x;

    const float s  = inv_sigma[0];
    const float k1 = -(s * s) * LOG2E;

    const float* __restrict__ Cb = C + (size_t)b * N * 3;
    const float cn0 = Cb[n * 3 + 0];
    const float cn1 = Cb[n * 3 + 1];
    const float cn2 = Cb[n * 3 + 2];
    const float sqn = cn0 * cn0 + cn1 * cn1 + cn2 * cn2;

    const int m0 = t * 4;
    const f32x4* __restrict__ cmp = (const f32x4*)(Cb + (size_t)m0 * 3);
    const f32x4 ca  = cmp[0];
    const f32x4 cb4 = cmp[1];
    const f32x4 cc  = cmp[2];

    const size_t rowbase = ((size_t)b * N + n) * N;
    const f32x4 mk = *(const f32x4*)(masks + rowbase + m0);

    const float x0 = calcx(ca.x,  ca.y,  ca.z,  mk.x, cn0, cn1, cn2, sqn, k1);
    const float x1 = calcx(ca.w,  cb4.x, cb4.y, mk.y, cn0, cn1, cn2, sqn, k1);
    const float x2 = calcx(cb4.z, cb4.w, cc.x,  mk.z, cn0, cn1, cn2, sqn, k1);
    const float x3 = calcx(cc.y,  cc.z,  cc.w,  mk.w, cn0, cn1, cn2, sqn, k1);

    float psum = (x0 + x1) + (x2 + x3);
    #pragma unroll
    for (int off = 32; off > 0; off >>= 1)
        psum += __shfl_xor(psum, off, 64);

    __shared__ float wsum[4];
    const int wid = t >> 6;
    if ((t & 63) == 0) wsum[wid] = psum;
    __syncthreads();

    const float total = wsum[0] + wsum[1] + wsum[2] + wsum[3];
    const float r = 1.0f / (total + EPS);

    f32x4 o;
    o.x = x0 * r; o.y = x1 * r; o.z = x2 * r; o.w = x3 * r;
    __builtin_nontemporal_store(o, (f32x4*)(out + rowbase + m0));
}

extern "C" void kernel_launch(void* const* d_in, const int* in_sizes, int n_in,
                              void* d_out, int out_size, void* d_ws, size_t ws_size,
                              hipStream_t stream) {
    const float* C         = (const float*)d_in[0];  // [B, N, 3]
    const float* masks     = (const float*)d_in[1];  // [B, N, N]
    const float* inv_sigma = (const float*)d_in[2];  // [1]
    float* out             = (float*)d_out;          // [B, N, N]

    const long long N_ll = (long long)out_size * 3LL / (long long)in_sizes[0];
    const int N = (int)N_ll;
    const int B = in_sizes[0] / (3 * N);

    if (N == 1024 && (B * N) % 16 == 0) {
        const int grid = B * N / 16;    // 4 waves/block x 4 rows/wave
        gaussian_rownorm_1024<<<grid, 256, 0, stream>>>(C, masks, inv_sigma, out);
    } else {
        dim3 grid(N, B);
        gaussian_rownorm_generic<<<grid, N / 4, 0, stream>>>(C, masks, inv_sigma, out, N);
    }
}